// Round 1
// baseline (281.666 us; speedup 1.0000x reference)
//
#include <hip/hip_runtime.h>
#include <cmath>

#define B_ 16
#define H_ 32
#define W_ 32
#define C_ 128
#define F_ 128
#define E_ 8
#define KSZ (3*3*C_*F_)      // 147456 floats per effective kernel
#define GFLAT (16*16*F_)     // 32768 gating flatten size

__device__ __forceinline__ float softplus_f(float v) {
  // numerically stable, matches jax.nn.softplus = log1p(exp(x))
  return log1pf(expf(-fabsf(v))) + fmaxf(v, 0.f);
}

// ---------------------------------------------------------------------------
// 3x3 SAME conv, NHWC, C=F=128. One block = one (b, h) output row, 512 thr:
// thread = (f = t&127, wq = t>>7), computes 8 w-columns for its f.
// x row neighborhood staged in LDS (3 rows x 34 cols x 128 c, zero-padded).
// PERB: kernel/bias are per-batch (expert path) vs shared (gating path).
// ---------------------------------------------------------------------------
template<bool PERB>
__global__ __launch_bounds__(512) void conv3x3_k(
    const float* __restrict__ x, const float* __restrict__ kern,
    const float* __restrict__ bias, float* __restrict__ out)
{
  const int b  = blockIdx.x >> 5;
  const int h0 = blockIdx.x & 31;
  const int t  = threadIdx.x;
  const int f  = t & 127;
  const int wq = t >> 7;
  const int w0 = wq * 8;

  __shared__ float xs[3][34][C_];   // 52,224 B

  const int NV = 3 * 34 * (C_ / 4);
  for (int v = t; v < NV; v += 512) {
    int c4  = v & 31;
    int rem = v >> 5;
    int lc  = rem % 34;
    int a   = rem / 34;
    int row = h0 - 1 + a;
    int w   = lc - 1;
    float4 val = make_float4(0.f, 0.f, 0.f, 0.f);
    if (row >= 0 && row < H_ && w >= 0 && w < W_)
      val = *(const float4*)&x[(((b * H_ + row) * W_ + w) * C_) + c4 * 4];
    *(float4*)&xs[a][lc][c4 * 4] = val;
  }
  __syncthreads();

  const float* kb = PERB ? (kern + (size_t)b * KSZ) : kern;

  float acc[8];
  #pragma unroll
  for (int i = 0; i < 8; ++i) acc[i] = 0.f;

  #pragma unroll
  for (int a = 0; a < 3; ++a) {            // a == kh (input row h0-1+a)
    for (int c4 = 0; c4 < C_ / 4; ++c4) {  // channel chunk of 4
      float kv[3][4];
      #pragma unroll
      for (int kw = 0; kw < 3; ++kw)
        #pragma unroll
        for (int cc = 0; cc < 4; ++cc)
          kv[kw][cc] = kb[(((a * 3 + kw) * C_) + c4 * 4 + cc) * F_ + f];
      #pragma unroll
      for (int j = 0; j < 10; ++j) {       // lds col = w0+j, w_abs = w0+j-1
        float4 xv = *(const float4*)&xs[a][w0 + j][c4 * 4];
        #pragma unroll
        for (int kw = 0; kw < 3; ++kw) {
          int wl = j - kw;                  // output col (local)
          if (wl < 0 || wl >= 8) continue;
          acc[wl] += xv.x * kv[kw][0] + xv.y * kv[kw][1]
                   + xv.z * kv[kw][2] + xv.w * kv[kw][3];
        }
      }
    }
  }

  const float bv = PERB ? bias[b * F_ + f] : bias[f];
  #pragma unroll
  for (int i = 0; i < 8; ++i)
    out[(((b * H_ + h0) * W_) + (w0 + i)) * F_ + f] = acc[i] + bv;
}

// ---------------------------------------------------------------------------
// 2x2 maxpool stride 2 on [B,32,32,128] -> [B,16,16,128]
// ---------------------------------------------------------------------------
__global__ __launch_bounds__(256) void pool_k(
    const float* __restrict__ g, float* __restrict__ pool)
{
  int i = blockIdx.x * 256 + threadIdx.x;       // < 524288
  int f    = i & 127;
  int rest = i >> 7;
  int pw   = rest & 15;  rest >>= 4;
  int ph   = rest & 15;
  int b    = rest >> 4;
  int base = (((b * H_ + ph * 2) * W_) + pw * 2) * F_ + f;
  float m = fmaxf(fmaxf(g[base], g[base + F_]),
                  fmaxf(g[base + W_ * F_], g[base + W_ * F_ + F_]));
  pool[i] = m;
}

// ---------------------------------------------------------------------------
// Per-batch: dense (32768 -> 8) + noisy logits + top-2 softmax gates
// + effective bias  eff_bias[b][f] = sum_e gates[b,e]*expert_bias[f,e]
// ---------------------------------------------------------------------------
__global__ __launch_bounds__(256) void gating_k(
    const float* __restrict__ pool, const float* __restrict__ Wg,
    const float* __restrict__ bg, const float* __restrict__ eps_gate,
    const float* __restrict__ ebias,
    float* __restrict__ gates, float* __restrict__ eff_bias)
{
  const int b = blockIdx.x;
  const int t = threadIdx.x;

  float acc[8];
  #pragma unroll
  for (int e = 0; e < 8; ++e) acc[e] = 0.f;

  for (int g = t; g < GFLAT; g += 256) {
    float p = pool[b * GFLAT + g];
    float4 wA = *(const float4*)&Wg[(size_t)g * 8];
    float4 wB = *(const float4*)&Wg[(size_t)g * 8 + 4];
    acc[0] += p * wA.x; acc[1] += p * wA.y;
    acc[2] += p * wA.z; acc[3] += p * wA.w;
    acc[4] += p * wB.x; acc[5] += p * wB.y;
    acc[6] += p * wB.z; acc[7] += p * wB.w;
  }

  __shared__ float red[256][8];
  #pragma unroll
  for (int e = 0; e < 8; ++e) red[t][e] = acc[e];
  __syncthreads();
  for (int s = 128; s > 0; s >>= 1) {
    if (t < s) {
      #pragma unroll
      for (int e = 0; e < 8; ++e) red[t][e] += red[t + s][e];
    }
    __syncthreads();
  }

  __shared__ float gl[8];
  if (t == 0) {
    float lg[8];
    #pragma unroll
    for (int e = 0; e < 8; ++e)
      lg[e] = red[0][e] + bg[e] + 1e-4f * eps_gate[b * 8 + e];
    // top-2 (ties -> lowest index, matching lax.top_k)
    int i0 = 0;
    #pragma unroll
    for (int e = 1; e < 8; ++e) if (lg[e] > lg[i0]) i0 = e;
    int i1 = (i0 == 0) ? 1 : 0;
    #pragma unroll
    for (int e = 0; e < 8; ++e)
      if (e != i0 && lg[e] > lg[i1]) i1 = e;
    float m  = fmaxf(lg[i0], lg[i1]);
    float e0 = expf(lg[i0] - m), e1 = expf(lg[i1] - m);
    float s  = e0 + e1;
    #pragma unroll
    for (int e = 0; e < 8; ++e) gl[e] = 0.f;
    gl[i0] = e0 / s; gl[i1] = e1 / s;
  }
  __syncthreads();

  if (t < 8) gates[b * 8 + t] = gl[t];
  if (t < F_) {
    float s = 0.f;
    #pragma unroll
    for (int e = 0; e < 8; ++e) s += gl[e] * ebias[t * 8 + e];
    eff_bias[b * F_ + t] = s;
  }
}

// ---------------------------------------------------------------------------
// Effective per-batch kernels:
//   eff_k[b][kh,kw,c,f] = sum_e gates[b,e]*(mu + softplus(rho[kw,c,f,e])*eps)
// One thread per (kh,kw,c,f) index, all 16 batches written. Single pass
// over mu/eps (coalesced 32B-per-thread reads).
// ---------------------------------------------------------------------------
__global__ __launch_bounds__(256) void effk_k(
    const float* __restrict__ mu, const float* __restrict__ rho,
    const float* __restrict__ eps, const float* __restrict__ gates,
    float* __restrict__ effk)
{
  __shared__ float gl[B_ * E_];
  const int t = threadIdx.x;
  if (t < B_ * E_) gl[t] = gates[t];
  __syncthreads();

  const int idx  = blockIdx.x * 256 + t;       // < 147456 (exact grid)
  const int f    = idx & 127;
  const int rest = idx >> 7;
  const int c    = rest & 127;
  const int kwkh = rest >> 7;                  // kh*3 + kw
  const int kw   = kwkh % 3;
  const int ridx = (kw * C_ + c) * F_ + f;     // rho shared over kh

  float4 m0 = *(const float4*)&mu [(size_t)idx  * 8];
  float4 m1 = *(const float4*)&mu [(size_t)idx  * 8 + 4];
  float4 e0 = *(const float4*)&eps[(size_t)idx  * 8];
  float4 e1 = *(const float4*)&eps[(size_t)idx  * 8 + 4];
  float4 r0 = *(const float4*)&rho[(size_t)ridx * 8];
  float4 r1 = *(const float4*)&rho[(size_t)ridx * 8 + 4];

  float k8[8];
  k8[0] = m0.x + softplus_f(r0.x) * e0.x;
  k8[1] = m0.y + softplus_f(r0.y) * e0.y;
  k8[2] = m0.z + softplus_f(r0.z) * e0.z;
  k8[3] = m0.w + softplus_f(r0.w) * e0.w;
  k8[4] = m1.x + softplus_f(r1.x) * e1.x;
  k8[5] = m1.y + softplus_f(r1.y) * e1.y;
  k8[6] = m1.z + softplus_f(r1.z) * e1.z;
  k8[7] = m1.w + softplus_f(r1.w) * e1.w;

  #pragma unroll
  for (int b = 0; b < B_; ++b) {
    float s = 0.f;
    #pragma unroll
    for (int e = 0; e < 8; ++e) s += gl[b * 8 + e] * k8[e];
    effk[(size_t)b * KSZ + idx] = s;
  }
}

// ---------------------------------------------------------------------------
extern "C" void kernel_launch(void* const* d_in, const int* in_sizes, int n_in,
                              void* d_out, int out_size, void* d_ws, size_t ws_size,
                              hipStream_t stream) {
  const float* x    = (const float*)d_in[0];
  const float* epsk = (const float*)d_in[1];
  const float* epsg = (const float*)d_in[2];
  const float* mu   = (const float*)d_in[3];
  const float* rho  = (const float*)d_in[4];
  const float* ebias= (const float*)d_in[5];
  const float* gk   = (const float*)d_in[6];
  const float* gb   = (const float*)d_in[7];
  const float* gok  = (const float*)d_in[8];
  const float* gob  = (const float*)d_in[9];
  float* out = (float*)d_out;

  float* ws    = (float*)d_ws;
  float* gtmp  = ws;                        // 2,097,152 (gating conv out)
  float* pool  = gtmp + (size_t)B_*H_*W_*F_;// 524,288
  float* gates = pool + (size_t)B_*GFLAT;   // 128
  float* effb  = gates + 128;               // 2,048
  float* effk  = effb + (size_t)B_*F_;      // 2,359,296   (total ~20 MB)

  // 1. gating conv (+bias)
  conv3x3_k<false><<<B_ * H_, 512, 0, stream>>>(x, gk, gb, gtmp);
  // 2. 2x2 maxpool
  pool_k<<<(B_ * GFLAT) / 256, 256, 0, stream>>>(gtmp, pool);
  // 3. dense -> noisy logits -> top-2 softmax gates + effective bias
  gating_k<<<B_, 256, 0, stream>>>(pool, gok, gob, epsg, ebias, gates, effb);
  // 4. per-batch effective kernel build
  effk_k<<<KSZ / 256, 256, 0, stream>>>(mu, rho, epsk, gates, effk);
  // 5. expert conv with per-batch kernel (+ effective bias)
  conv3x3_k<true><<<B_ * H_, 512, 0, stream>>>(x, effk, effb, out);
}

// Round 2
// 108.727 us; speedup vs baseline: 2.5906x; 2.5906x over previous
//
#include <hip/hip_runtime.h>
#include <cmath>

#define B_ 16
#define H_ 32
#define W_ 32
#define C_ 128
#define F_ 128
#define E_ 8
#define KSZ (9*C_*F_)        // 147456 elems per effective kernel
#define NKS 36               // K-steps of 32 (9 taps x 4 c-chunks)
#define FRAG_ELE 4096        // elems per K-step fragment chunk = 8nf*64l*8j

typedef __bf16 bf16;
typedef __bf16 bf16x8 __attribute__((ext_vector_type(8)));
typedef float  f32x4  __attribute__((ext_vector_type(4)));

__device__ __forceinline__ float softplus_f(float v) {
  return log1pf(expf(-fabsf(v))) + fmaxf(v, 0.f);
}

// ---------------------------------------------------------------------------
// MFMA 3x3 SAME conv. Block = (b, h): M=32 pixels (w), N=128 (f), K=1152.
// 8 waves: wave covers 16 M-rows x 32 N-cols (2 n-frags), mfma 16x16x32 bf16.
// A: x rows staged in LDS (bf16, XOR-swizzled to kill 256B-stride conflicts).
// B: kernel pre-arranged in global in fragment order [ks][nf][lane][8],
//    staged per K-step into LDS (contiguous, conflict-free lane-linear reads).
// NVAR==2: split-precision gating conv: acc = Ah*Bh + Al*Bh + Ah*Bl.
// NVAR==1: expert conv, per-batch B (Bhi + b*KSZ) and per-batch bias.
// ---------------------------------------------------------------------------
template<int NVAR>
__global__ __launch_bounds__(512) void conv_mfma_k(
    const bf16* __restrict__ xhi, const bf16* __restrict__ xlo,
    const bf16* __restrict__ Bhi, const bf16* __restrict__ Blo,
    const float* __restrict__ bias, float* __restrict__ out)
{
  const int b   = blockIdx.x >> 5;
  const int h0  = blockIdx.x & 31;
  const int t   = threadIdx.x;
  const int l   = t & 63;
  const int wid = t >> 6;

  __shared__ bf16 xs[NVAR*3*34*128];   // swizzled; 26112B per variant
  __shared__ bf16 Bs[FRAG_ELE];        // 8192B, one K-step of one variant

  // ---- stage x neighborhood rows into swizzled LDS (hi[, lo]) ----
  const int NCH = NVAR*3*34*16;        // 16B chunks
  for (int v = t; v < NCH; v += 512) {
    int c8  = v & 15;
    int col = (v >> 4) % 34;
    int rem = (v >> 4) / 34;
    int kh  = rem % 3;
    int var = rem / 3;
    int row = h0 - 1 + kh;
    int w   = col - 1;
    int off = ((var*3 + kh)*34 + col)*256 + c8*16;
    off ^= (col & 7) << 4;
    int4 val = make_int4(0,0,0,0);
    if (row >= 0 && row < H_ && w >= 0 && w < W_) {
      const bf16* src = var ? xlo : xhi;
      val = *(const int4*)&src[((b*H_ + row)*W_ + w)*C_ + c8*8];
    }
    *(int4*)((char*)xs + off) = val;
  }

  const bf16* Bh = Bhi + (NVAR == 1 ? (size_t)b*KSZ : (size_t)0);

  const int mr0 = (wid & 1) * 16;
  const int nf0 = (wid >> 1) * 2;

  f32x4 acc0 = {0.f,0.f,0.f,0.f};
  f32x4 acc1 = {0.f,0.f,0.f,0.f};

  const int arow  = mr0 + (l & 15);
  const int cpart = (l >> 4) * 8;

  for (int ks = 0; ks < NKS; ++ks) {
    const int khkw = ks >> 2;
    const int kh = khkw / 3;
    const int kw = khkw % 3;
    const int c0 = (ks & 3) * 32;
    const int col = arow + kw;
    int offA = (kh*34 + col)*256 + (c0 + cpart)*2;
    offA ^= (col & 7) << 4;

    for (int sub = 0; sub < NVAR; ++sub) {
      // stage B chunk for this (ks, variant): 512 thr x 16B = 8KB
      const bf16* bsrc = (sub == 0 ? Bh : Blo) + (size_t)ks*FRAG_ELE + t*8;
      int4 breg = *(const int4*)bsrc;
      __syncthreads();                      // prior reads of Bs complete
      *(int4*)((char*)Bs + t*16) = breg;
      __syncthreads();                      // Bs visible

      bf16x8 b0 = *(const bf16x8*)((const char*)Bs + nf0*1024 + l*16);
      bf16x8 b1 = *(const bf16x8*)((const char*)Bs + nf0*1024 + 1024 + l*16);
      bf16x8 a0 = *(const bf16x8*)((const char*)xs + offA);
      acc0 = __builtin_amdgcn_mfma_f32_16x16x32_bf16(a0, b0, acc0, 0, 0, 0);
      acc1 = __builtin_amdgcn_mfma_f32_16x16x32_bf16(a0, b1, acc1, 0, 0, 0);
      if (NVAR == 2 && sub == 0) {
        // x_lo * k_hi  (var offset 26112 is a multiple of 256: swizzle-safe)
        bf16x8 a1 = *(const bf16x8*)((const char*)xs + 3*34*256 + offA);
        acc0 = __builtin_amdgcn_mfma_f32_16x16x32_bf16(a1, b0, acc0, 0, 0, 0);
        acc1 = __builtin_amdgcn_mfma_f32_16x16x32_bf16(a1, b1, acc1, 0, 0, 0);
      }
    }
  }

  // epilogue: C/D layout col = l&15 (f), row = (l>>4)*4 + r (w)
  const int fcol = nf0*16 + (l & 15);
  const int wrow = mr0 + (l >> 4)*4;
  const int bb   = (NVAR == 1) ? b*F_ : 0;
  const float bv0 = bias[bb + fcol];
  const float bv1 = bias[bb + fcol + 16];
  #pragma unroll
  for (int r = 0; r < 4; ++r) {
    int o = ((b*H_ + h0)*W_ + (wrow + r))*F_;
    out[o + fcol]      = acc0[r] + bv0;
    out[o + fcol + 16] = acc1[r] + bv1;
  }
}

// ---------------------------------------------------------------------------
// Gating tail: fused 2x2 maxpool + dense (32768->8) + noisy top-2 softmax
// gates + effective bias. One block per batch, 1024 threads.
// ---------------------------------------------------------------------------
__global__ __launch_bounds__(1024) void gating_k(
    const float* __restrict__ g, const float* __restrict__ Wg,
    const float* __restrict__ bg, const float* __restrict__ eps_gate,
    const float* __restrict__ ebias,
    float* __restrict__ gates, float* __restrict__ eff_bias)
{
  const int b = blockIdx.x;
  const int t = threadIdx.x;

  float acc[8];
  #pragma unroll
  for (int e = 0; e < 8; ++e) acc[e] = 0.f;

  for (int i = t; i < 16*16*F_; i += 1024) {
    int f  = i & 127;
    int pw = (i >> 7) & 15;
    int ph = i >> 11;
    int base = ((b*H_ + ph*2)*W_ + pw*2)*F_ + f;
    float p = fmaxf(fmaxf(g[base], g[base + F_]),
                    fmaxf(g[base + W_*F_], g[base + W_*F_ + F_]));
    float4 wA = *(const float4*)&Wg[(size_t)i*8];
    float4 wB = *(const float4*)&Wg[(size_t)i*8 + 4];
    acc[0] += p*wA.x; acc[1] += p*wA.y; acc[2] += p*wA.z; acc[3] += p*wA.w;
    acc[4] += p*wB.x; acc[5] += p*wB.y; acc[6] += p*wB.z; acc[7] += p*wB.w;
  }

  __shared__ float red[1024][8];
  #pragma unroll
  for (int e = 0; e < 8; ++e) red[t][e] = acc[e];
  __syncthreads();
  for (int s = 512; s > 0; s >>= 1) {
    if (t < s) {
      #pragma unroll
      for (int e = 0; e < 8; ++e) red[t][e] += red[t + s][e];
    }
    __syncthreads();
  }

  __shared__ float gl[8];
  if (t == 0) {
    float lg[8];
    #pragma unroll
    for (int e = 0; e < 8; ++e)
      lg[e] = red[0][e] + bg[e] + 1e-4f * eps_gate[b*8 + e];
    int i0 = 0;
    #pragma unroll
    for (int e = 1; e < 8; ++e) if (lg[e] > lg[i0]) i0 = e;
    int i1 = (i0 == 0) ? 1 : 0;
    #pragma unroll
    for (int e = 0; e < 8; ++e)
      if (e != i0 && lg[e] > lg[i1]) i1 = e;
    float m  = fmaxf(lg[i0], lg[i1]);
    float e0 = expf(lg[i0] - m), e1 = expf(lg[i1] - m);
    float s  = e0 + e1;
    #pragma unroll
    for (int e = 0; e < 8; ++e) gl[e] = 0.f;
    gl[i0] = e0 / s; gl[i1] = e1 / s;
  }
  __syncthreads();

  if (t < 8) gates[b*8 + t] = gl[t];
  if (t < F_) {
    float s = 0.f;
    #pragma unroll
    for (int e = 0; e < 8; ++e) s += gl[e] * ebias[t*8 + e];
    eff_bias[b*F_ + t] = s;
  }
}

// ---------------------------------------------------------------------------
// Effective per-batch kernels, written as bf16 in MFMA fragment order:
// Bg[b][ks][nf][lane][j] = sum_e gates[b,e]*(mu + softplus(rho)*eps)
// at (khkw=ks>>2, c=(ks&3)*32+(l>>4)*8+j, f=nf*16+(l&15)).
// Block = (ks, batch-half): one pass over the mu/eps slice for 8 batches.
// ---------------------------------------------------------------------------
__global__ __launch_bounds__(512) void effk_frag_k(
    const float* __restrict__ mu, const float* __restrict__ rho,
    const float* __restrict__ eps, const float* __restrict__ gates,
    bf16* __restrict__ Bg)
{
  const int ks = blockIdx.x >> 1;
  const int bh = (blockIdx.x & 1) * 8;
  __shared__ float gl[128];
  if (threadIdx.x < 128) gl[threadIdx.x] = gates[threadIdx.x];
  __syncthreads();

  const int nf = threadIdx.x >> 6;
  const int l  = threadIdx.x & 63;
  const int khkw = ks >> 2;
  const int kw   = khkw % 3;
  const int f    = nf*16 + (l & 15);
  const int cb   = (ks & 3)*32 + (l >> 4)*8;

  bf16x8 ob[8];
  #pragma unroll
  for (int j = 0; j < 8; ++j) {
    const int c = cb + j;
    const float* mp = &mu [(size_t)((khkw*C_ + c)*F_ + f) * E_];
    const float* ep = &eps[(size_t)((khkw*C_ + c)*F_ + f) * E_];
    const float* rp = &rho[(size_t)((kw  *C_ + c)*F_ + f) * E_];
    float kv[8];
    #pragma unroll
    for (int e = 0; e < 8; ++e)
      kv[e] = mp[e] + softplus_f(rp[e]) * ep[e];
    #pragma unroll
    for (int bb = 0; bb < 8; ++bb) {
      const float* gp = &gl[(bh + bb)*8];
      float s = 0.f;
      #pragma unroll
      for (int e = 0; e < 8; ++e) s += gp[e] * kv[e];
      ob[bb][j] = (bf16)s;
    }
  }
  #pragma unroll
  for (int bb = 0; bb < 8; ++bb) {
    size_t o = (((size_t)(bh + bb)*NKS + ks)*8 + nf)*512 + l*8;
    *(bf16x8*)&Bg[o] = ob[bb];
  }
}

// ---------------------------------------------------------------------------
// Conversions: x -> bf16 hi/lo (natural layout); gating_kernel -> bf16 hi/lo
// in MFMA fragment order.
// ---------------------------------------------------------------------------
__global__ __launch_bounds__(256) void convert_k(
    const float* __restrict__ x, const float* __restrict__ gk,
    bf16* __restrict__ xhi, bf16* __restrict__ xlo,
    bf16* __restrict__ bgh, bf16* __restrict__ bgl)
{
  const int bid = blockIdx.x;
  if (bid < 576) {                       // gating kernel: 147456 elems
    int flat = bid*256 + threadIdx.x;
    int j  = flat & 7;
    int l  = (flat >> 3) & 63;
    int nf = (flat >> 9) & 7;
    int ks = flat >> 12;
    int khkw = ks >> 2;
    int c = (ks & 3)*32 + (l >> 4)*8 + j;
    int f = nf*16 + (l & 15);
    float v = gk[(khkw*C_ + c)*F_ + f];
    bf16 h = (bf16)v;
    bgh[flat] = h;
    bgl[flat] = (bf16)(v - (float)h);
  } else {                               // x: 2097152 elems, 8 per thread
    int idx = (bid - 576)*256 + threadIdx.x;
    const float4* xp = (const float4*)x;
    float4 v0 = xp[(size_t)idx*2];
    float4 v1 = xp[(size_t)idx*2 + 1];
    float vv[8] = {v0.x, v0.y, v0.z, v0.w, v1.x, v1.y, v1.z, v1.w};
    bf16x8 h8, l8;
    #pragma unroll
    for (int j = 0; j < 8; ++j) {
      bf16 h = (bf16)vv[j];
      h8[j] = h;
      l8[j] = (bf16)(vv[j] - (float)h);
    }
    *(bf16x8*)&xhi[(size_t)idx*8] = h8;
    *(bf16x8*)&xlo[(size_t)idx*8] = l8;
  }
}

// ---------------------------------------------------------------------------
extern "C" void kernel_launch(void* const* d_in, const int* in_sizes, int n_in,
                              void* d_out, int out_size, void* d_ws, size_t ws_size,
                              hipStream_t stream) {
  const float* x    = (const float*)d_in[0];
  const float* epsk = (const float*)d_in[1];
  const float* epsg = (const float*)d_in[2];
  const float* mu   = (const float*)d_in[3];
  const float* rho  = (const float*)d_in[4];
  const float* ebias= (const float*)d_in[5];
  const float* gk   = (const float*)d_in[6];
  const float* gb   = (const float*)d_in[7];
  const float* gok  = (const float*)d_in[8];
  const float* gob  = (const float*)d_in[9];
  float* out = (float*)d_out;

  char* ws = (char*)d_ws;
  bf16*  xhi   = (bf16*) (ws);                  // 4,194,304 B
  bf16*  xlo   = (bf16*) (ws + 4194304);        // 4,194,304 B
  bf16*  bgh   = (bf16*) (ws + 8388608);        //   294,912 B
  bf16*  bgl   = (bf16*) (ws + 8683520);        //   294,912 B
  float* gtmp  = (float*)(ws + 8978432);        // 8,388,608 B
  bf16*  bge   = (bf16*) (ws + 8978432);        // aliases gtmp (dead by then)
  float* gates = (float*)(ws + 17367040);       //       512 B
  float* effb  = (float*)(ws + 17367552);       //     8,192 B  (end ~16.6MB)

  // 1. conversions (x hi/lo, gating kernel hi/lo frag-ordered)
  convert_k<<<1600, 256, 0, stream>>>(x, gk, xhi, xlo, bgh, bgl);
  // 2. gating conv, split-bf16 MFMA (+bias) -> gtmp f32
  conv_mfma_k<2><<<B_*H_, 512, 0, stream>>>(xhi, xlo, bgh, bgl, gb, gtmp);
  // 3. fused pool + dense + noisy top-2 gates + effective bias
  gating_k<<<B_, 1024, 0, stream>>>(gtmp, gok, gob, epsg, ebias, gates, effb);
  // 4. per-batch effective kernel, bf16 fragment order (over gtmp region)
  effk_frag_k<<<NKS*2, 512, 0, stream>>>(mu, rho, epsk, gates, bge);
  // 5. expert conv, bf16 MFMA, per-batch kernel + bias
  conv_mfma_k<1><<<B_*H_, 512, 0, stream>>>(xhi, xhi, bge, bge, effb, out);
}

// Round 3
// 76.234 us; speedup vs baseline: 3.6948x; 1.4262x over previous
//
#include <hip/hip_runtime.h>
#include <cmath>

#define B_ 16
#define H_ 32
#define W_ 32
#define C_ 128
#define F_ 128
#define KSZ (9*C_*F_)        // 147456 elems per effective kernel
#define NKS 36               // K-steps of 32 (9 taps x 4 c-chunks)
#define FRAG_ELE 4096        // elems per K-step fragment chunk

typedef __bf16 bf16;
typedef __bf16 bf16x4 __attribute__((ext_vector_type(4)));
typedef __bf16 bf16x8 __attribute__((ext_vector_type(8)));
typedef float  f32x4  __attribute__((ext_vector_type(4)));

__device__ __forceinline__ float softplus_f(float v) {
  return log1pf(expf(-fabsf(v))) + fmaxf(v, 0.f);
}

#define MFMA16(a, bb, c) __builtin_amdgcn_mfma_f32_16x16x32_bf16(a, bb, c, 0, 0, 0)

// ---------------------------------------------------------------------------
// MFMA 3x3 SAME conv, block = (b, h-pair): M=64 (2 h-rows x 32 w), N=128,
// K=1152. 8 waves, wave = 2 m-frags (mpar, mpar+2) x 2 n-frags.
// A: x staged f32->bf16 (hi[,lo]) into XOR-swizzled LDS; one barrier total.
// B: fragment-ordered in global [ks][nf][lane][8]; each wave loads its own
//    frags directly (coalesced 16B/lane), 1-deep manual prefetch, NO LDS/barriers.
// NVAR==2: split-precision gating conv (Ah*Bh + Al*Bh + Ah*Bl), epilogue
//          fuses 2x2 maxpool + dense partial -> part[b][hb][8].
// NVAR==1: expert conv, per-batch B + bias, writes final output.
// ---------------------------------------------------------------------------
template<int NVAR>
__global__ __launch_bounds__(512) void conv_k(
    const float* __restrict__ x,
    const bf16* __restrict__ Bhi, const bf16* __restrict__ Blo,
    const float* __restrict__ bias,
    const float* __restrict__ Wg,
    float* __restrict__ out)
{
  const int b  = blockIdx.x >> 4;
  const int hb = blockIdx.x & 15;
  const int t  = threadIdx.x;

  __shared__ bf16 xs[NVAR*4*34*128];   // 34816B per variant, swizzled
  __shared__ float red[8][8];

  // ---- stage x (4 rows x 34 cols x 128c), f32 -> bf16 hi(/lo), swizzled ----
  for (int v = t; v < 4*34*32; v += 512) {
    int c4   = v & 31;
    int col  = (v >> 5) % 34;
    int rowi = (v >> 5) / 34;
    int row  = hb*2 - 1 + rowi;
    int w    = col - 1;
    float4 xv = make_float4(0.f, 0.f, 0.f, 0.f);
    if (row >= 0 && row < H_ && w >= 0 && w < W_)
      xv = *(const float4*)&x[((b*H_ + row)*W_ + w)*C_ + c4*4];
    float vv[4] = {xv.x, xv.y, xv.z, xv.w};
    bf16x4 h4, l4;
    #pragma unroll
    for (int j = 0; j < 4; ++j) {
      h4[j] = (bf16)vv[j];
      if (NVAR == 2) l4[j] = (bf16)(vv[j] - (float)h4[j]);
    }
    int base = ((rowi*34 + col)*256 + c4*8) ^ ((col & 7) << 4);
    *(bf16x4*)((char*)xs + base) = h4;
    if (NVAR == 2) *(bf16x4*)((char*)xs + 34816 + base) = l4;
  }
  __syncthreads();

  const int l    = t & 63;
  const int wid  = t >> 6;
  const int mpar = wid & 1;            // m-frags mpar, mpar+2  (h_local 0,1)
  const int nf0  = (wid >> 1) << 1;    // n-frags nf0, nf0+1
  const int r15  = l & 15;
  const int q    = l >> 4;

  f32x4 acc00 = {0.f,0.f,0.f,0.f}, acc01 = acc00, acc10 = acc00, acc11 = acc00;

  const bf16* Bh = Bhi + (NVAR == 1 ? (size_t)b * KSZ : (size_t)0);
  const size_t bgo = (size_t)(nf0*512 + l*8);

  bf16x8 bh0 = *(const bf16x8*)(Bh + bgo);
  bf16x8 bh1 = *(const bf16x8*)(Bh + bgo + 512);
  bf16x8 bl0 = bh0, bl1 = bh1;
  if (NVAR == 2) {
    bl0 = *(const bf16x8*)(Blo + bgo);
    bl1 = *(const bf16x8*)(Blo + bgo + 512);
  }

  for (int ks = 0; ks < NKS; ++ks) {
    bf16x8 nh0 = bh0, nh1 = bh1, nl0 = bl0, nl1 = bl1;
    if (ks + 1 < NKS) {
      size_t o = bgo + (size_t)(ks + 1) * FRAG_ELE;
      nh0 = *(const bf16x8*)(Bh + o);
      nh1 = *(const bf16x8*)(Bh + o + 512);
      if (NVAR == 2) {
        nl0 = *(const bf16x8*)(Blo + o);
        nl1 = *(const bf16x8*)(Blo + o + 512);
      }
    }
    const int khkw = ks >> 2;
    const int kh = khkw / 3, kw = khkw % 3;
    const int c0 = (ks & 3) << 5;
    const int col = mpar*16 + r15 + kw;
    const int off = ((kh*34 + col)*256 + (c0 + q*8)*2) ^ ((col & 7) << 4);

    bf16x8 a0 = *(const bf16x8*)((const char*)xs + off);          // h_local 0
    bf16x8 a1 = *(const bf16x8*)((const char*)xs + off + 8704);   // h_local 1
    acc00 = MFMA16(a0, bh0, acc00);
    acc01 = MFMA16(a0, bh1, acc01);
    acc10 = MFMA16(a1, bh0, acc10);
    acc11 = MFMA16(a1, bh1, acc11);
    if (NVAR == 2) {
      bf16x8 g0 = *(const bf16x8*)((const char*)xs + 34816 + off);
      bf16x8 g1 = *(const bf16x8*)((const char*)xs + 34816 + off + 8704);
      acc00 = MFMA16(g0, bh0, acc00);
      acc01 = MFMA16(g0, bh1, acc01);
      acc10 = MFMA16(g1, bh0, acc10);
      acc11 = MFMA16(g1, bh1, acc11);
      acc00 = MFMA16(a0, bl0, acc00);
      acc01 = MFMA16(a0, bl1, acc01);
      acc10 = MFMA16(a1, bl0, acc10);
      acc11 = MFMA16(a1, bl1, acc11);
    }
    bh0 = nh0; bh1 = nh1; bl0 = nl0; bl1 = nl1;
  }

  // C/D layout: col(f) = l&15, row(m within frag) = q*4 + r
  if (NVAR == 1) {
    const int f0 = nf0*16 + r15;
    const float bv0 = bias[b*F_ + f0];
    const float bv1 = bias[b*F_ + f0 + 16];
    #pragma unroll
    for (int mi = 0; mi < 2; ++mi) {
      const int h = hb*2 + mi;
      #pragma unroll
      for (int r = 0; r < 4; ++r) {
        const int wo = mpar*16 + q*4 + r;
        float* o = &out[((b*H_ + h)*W_ + wo)*F_];
        o[f0]      = (mi ? acc10[r] : acc00[r]) + bv0;
        o[f0 + 16] = (mi ? acc11[r] : acc01[r]) + bv1;
      }
    }
  } else {
    float part[8] = {0,0,0,0,0,0,0,0};
    #pragma unroll
    for (int ni = 0; ni < 2; ++ni) {
      const int f = (nf0 + ni)*16 + r15;
      const float bv = bias[f];
      #pragma unroll
      for (int pp = 0; pp < 2; ++pp) {
        float m0 = ni ? fmaxf(acc01[2*pp], acc01[2*pp+1])
                      : fmaxf(acc00[2*pp], acc00[2*pp+1]);
        float m1 = ni ? fmaxf(acc11[2*pp], acc11[2*pp+1])
                      : fmaxf(acc10[2*pp], acc10[2*pp+1]);
        float pm = fmaxf(m0, m1) + bv;
        const int pw = mpar*8 + q*2 + pp;
        const float* wr = &Wg[(size_t)((hb*16 + pw)*128 + f) * 8];
        float4 wA = *(const float4*)wr;
        float4 wB = *(const float4*)(wr + 4);
        part[0] += pm*wA.x; part[1] += pm*wA.y;
        part[2] += pm*wA.z; part[3] += pm*wA.w;
        part[4] += pm*wB.x; part[5] += pm*wB.y;
        part[6] += pm*wB.z; part[7] += pm*wB.w;
      }
    }
    #pragma unroll
    for (int o = 32; o > 0; o >>= 1)
      #pragma unroll
      for (int e = 0; e < 8; ++e) part[e] += __shfl_down(part[e], o);
    if (l == 0)
      #pragma unroll
      for (int e = 0; e < 8; ++e) red[wid][e] = part[e];
    __syncthreads();
    if (t < 8) {
      float s = 0.f;
      #pragma unroll
      for (int w = 0; w < 8; ++w) s += red[w][t];
      out[(b*16 + hb)*8 + t] = s;   // partial logits
    }
  }
}

// ---------------------------------------------------------------------------
// logits tail: sum partials + bias + noise -> top-2 softmax gates + eff bias
// ---------------------------------------------------------------------------
__global__ __launch_bounds__(256) void gates_k(
    const float* __restrict__ part, const float* __restrict__ gob,
    const float* __restrict__ epsg, const float* __restrict__ ebias,
    float* __restrict__ gates, float* __restrict__ effb)
{
  __shared__ float lgs[16][8];
  __shared__ float gl[16][8];
  const int t = threadIdx.x;
  if (t < 128) {
    int bb = t >> 3, e = t & 7;
    float s = 0.f;
    for (int hb = 0; hb < 16; ++hb) s += part[(bb*16 + hb)*8 + e];
    lgs[bb][e] = s + gob[e] + 1e-4f * epsg[bb*8 + e];
  }
  __syncthreads();
  if (t < 16) {
    float lg[8];
    #pragma unroll
    for (int e = 0; e < 8; ++e) lg[e] = lgs[t][e];
    int i0 = 0;
    #pragma unroll
    for (int e = 1; e < 8; ++e) if (lg[e] > lg[i0]) i0 = e;
    int i1 = (i0 == 0) ? 1 : 0;
    #pragma unroll
    for (int e = 0; e < 8; ++e)
      if (e != i0 && lg[e] > lg[i1]) i1 = e;
    float m  = fmaxf(lg[i0], lg[i1]);
    float e0 = expf(lg[i0] - m), e1 = expf(lg[i1] - m);
    float s  = e0 + e1;
    #pragma unroll
    for (int e = 0; e < 8; ++e) gl[t][e] = 0.f;
    gl[t][i0] = e0 / s;
    gl[t][i1] = e1 / s;
  }
  __syncthreads();
  if (t < 128) gates[t] = gl[t >> 3][t & 7];
  for (int i = t; i < B_*F_; i += 256) {
    int bb = i >> 7, f = i & 127;
    float s = 0.f;
    #pragma unroll
    for (int e = 0; e < 8; ++e) s += gl[bb][e] * ebias[f*8 + e];
    effb[i] = s;
  }
}

// ---------------------------------------------------------------------------
// Effective per-batch kernels in bf16 MFMA fragment order.
// Block = (ks, nf-half, batch-quarter): grid 288, 256 thr (4 nf x 64 lanes).
// ---------------------------------------------------------------------------
__global__ __launch_bounds__(256) void effk_k(
    const float* __restrict__ mu, const float* __restrict__ rho,
    const float* __restrict__ eps, const float* __restrict__ gates,
    bf16* __restrict__ Bg)
{
  const int ks  = blockIdx.x >> 3;
  const int rem = blockIdx.x & 7;
  const int nf  = (rem & 1)*4 + (threadIdx.x >> 6);
  const int bq  = (rem >> 1) * 4;
  __shared__ float gl[128];
  if (threadIdx.x < 128) gl[threadIdx.x] = gates[threadIdx.x];
  __syncthreads();

  const int l    = threadIdx.x & 63;
  const int khkw = ks >> 2;
  const int kw   = khkw % 3;
  const int f    = nf*16 + (l & 15);
  const int cb   = (ks & 3)*32 + (l >> 4)*8;

  bf16x8 ob[4];
  #pragma unroll
  for (int j = 0; j < 8; ++j) {
    const int c = cb + j;
    const float* mp = &mu [(size_t)((khkw*C_ + c)*F_ + f) * 8];
    const float* ep = &eps[(size_t)((khkw*C_ + c)*F_ + f) * 8];
    const float* rp = &rho[(size_t)((kw  *C_ + c)*F_ + f) * 8];
    float kv[8];
    #pragma unroll
    for (int e = 0; e < 8; ++e)
      kv[e] = mp[e] + softplus_f(rp[e]) * ep[e];
    #pragma unroll
    for (int bb = 0; bb < 4; ++bb) {
      const float* gp = &gl[(bq + bb)*8];
      float s = 0.f;
      #pragma unroll
      for (int e = 0; e < 8; ++e) s += gp[e] * kv[e];
      ob[bb][j] = (bf16)s;
    }
  }
  #pragma unroll
  for (int bb = 0; bb < 4; ++bb) {
    size_t o = (size_t)(bq + bb)*KSZ + (size_t)ks*FRAG_ELE + nf*512 + l*8;
    *(bf16x8*)&Bg[o] = ob[bb];
  }
}

// ---------------------------------------------------------------------------
// gating_kernel f32 -> bf16 hi/lo, fragment-ordered
// ---------------------------------------------------------------------------
__global__ __launch_bounds__(256) void gkconv_k(
    const float* __restrict__ gk, bf16* __restrict__ bgh, bf16* __restrict__ bgl)
{
  int flat = blockIdx.x*256 + threadIdx.x;     // < 147456
  int j  = flat & 7;
  int l  = (flat >> 3) & 63;
  int nf = (flat >> 9) & 7;
  int ks = flat >> 12;
  int khkw = ks >> 2;
  int c = (ks & 3)*32 + (l >> 4)*8 + j;
  int f = nf*16 + (l & 15);
  float v = gk[(khkw*C_ + c)*F_ + f];
  bf16 h = (bf16)v;
  bgh[flat] = h;
  bgl[flat] = (bf16)(v - (float)h);
}

// ---------------------------------------------------------------------------
extern "C" void kernel_launch(void* const* d_in, const int* in_sizes, int n_in,
                              void* d_out, int out_size, void* d_ws, size_t ws_size,
                              hipStream_t stream) {
  const float* x    = (const float*)d_in[0];
  const float* epsk = (const float*)d_in[1];
  const float* epsg = (const float*)d_in[2];
  const float* mu   = (const float*)d_in[3];
  const float* rho  = (const float*)d_in[4];
  const float* ebias= (const float*)d_in[5];
  const float* gk   = (const float*)d_in[6];
  const float* gb   = (const float*)d_in[7];
  const float* gok  = (const float*)d_in[8];
  const float* gob  = (const float*)d_in[9];
  float* out = (float*)d_out;

  char* ws = (char*)d_ws;
  bf16*  bgh   = (bf16*) (ws);                  //   294,912 B
  bf16*  bgl   = (bf16*) (ws + 294912);         //   294,912 B
  bf16*  bge   = (bf16*) (ws + 589824);         // 4,718,592 B
  float* part  = (float*)(ws + 5308416);        //     8,192 B
  float* gates = (float*)(ws + 5316608);        //       512 B
  float* effb  = (float*)(ws + 5317120);        //     8,192 B  (~5.3 MB)

  // 1. gating kernel -> bf16 hi/lo fragment order
  gkconv_k<<<576, 256, 0, stream>>>(gk, bgh, bgl);
  // 2. gating conv (split bf16, fused pool + dense partials)
  conv_k<2><<<B_*16, 512, 0, stream>>>(x, bgh, bgl, gb, gok, part);
  // 3. logits -> top-2 gates + effective bias
  gates_k<<<1, 256, 0, stream>>>(part, gob, epsg, ebias, gates, effb);
  // 4. per-batch effective kernel (bf16, fragment order)
  effk_k<<<NKS*8, 256, 0, stream>>>(mu, rho, epsk, gates, bge);
  // 5. expert conv (per-batch kernel + bias) -> output
  conv_k<1><<<B_*16, 512, 0, stream>>>(x, bge, bge, effb, nullptr, out);
}